// Round 18
// baseline (1047.277 us; speedup 1.0000x reference)
//
#include <hip/hip_runtime.h>

// SimpleRNN: x(256,2048,8) f32, h(1,256,128), W_ih(128,8), W_hh(128,128),
// b_ih(128), b_hh(128), W_head(1,128), b_head(1)
// out = [pred(256) | last_step_features(256,128) | h_n(256,128)]  (f32)
//
// R16: SINGLE WAVE PER BATCH ROW, ZERO BARRIERS (R4-verified ordering:
// DS ops are in-order within a wave => reads of step t+1 see step t's
// write without any sync). 256 blocks x 64 threads.
// Lane l owns outputs j0=2l, j0+1. W_hh rows in fp16: 128 f16x2 VGPRs
// (cvt results => non-remat, R6/R7-proven). h in LDS as f16 (256 B,
// SINGLE buffer): write 1 b32/lane, read 16 b128 wave-broadcasts at
// compile-time offsets. Dot via v_dot2_f32_f16 BUILTIN (f32 accumulate;
// R7's failure attributed to hand-asm VOP3P op_sel_hi default).
// x stays f32 (direct global, depth-2 pipeline, R10-verified).
// fp16 numerics = R5/R6 (passed, absmax 3.9e-3).

typedef _Float16 f16x2 __attribute__((ext_vector_type(2)));
typedef float f32x4 __attribute__((ext_vector_type(4)));
typedef float f32x2 __attribute__((ext_vector_type(2)));

#define BB 256
#define TT 2048
#define II 8
#define HH 128

#if __has_builtin(__builtin_amdgcn_fdot2)
#define FDOT2(h2, w2, acc) acc = __builtin_amdgcn_fdot2((h2), (w2), (acc), false)
#else
#define FDOT2(h2, w2, acc) \
    asm("v_dot2_f32_f16 %0, %1, %2, %0 op_sel:[0,0,0] op_sel_hi:[1,1,1]" \
        : "+v"(acc) : "v"(h2), "v"(w2))
#endif

__global__ void
__launch_bounds__(64, 1)
__attribute__((amdgpu_waves_per_eu(1, 1)))
rnn_v16_kernel(const float* __restrict__ x,
               const float* __restrict__ h0,
               const float* __restrict__ W_ih,
               const float* __restrict__ W_hh,
               const float* __restrict__ b_ih,
               const float* __restrict__ b_hh,
               const float* __restrict__ W_head,
               const float* __restrict__ b_head,
               float* __restrict__ out)
{
    __shared__ __align__(16) _Float16 hl[HH];   // single f16 h buffer, 256 B

    const int b  = blockIdx.x;
    const int l  = threadIdx.x;      // lane 0..63
    const int j0 = 2 * l;

    // ---- fp16 weight pack: wA[p]=(W[j0][2p],W[j0][2p+1]), wB for j0+1 ----
    f16x2 wA[64], wB[64];
    {
        const float* r0 = W_hh + (size_t)j0 * HH;
        const float* r1 = r0 + HH;
        #pragma unroll
        for (int p = 0; p < 64; ++p) {
            f16x2 a, c;
            a.x = (_Float16)r0[2 * p]; a.y = (_Float16)r0[2 * p + 1];
            c.x = (_Float16)r1[2 * p]; c.y = (_Float16)r1[2 * p + 1];
            wA[p] = a; wB[p] = c;
        }
    }
    // x-projection weights f32 (8 per output)
    float wxA[II], wxB[II];
    #pragma unroll
    for (int i = 0; i < II; ++i) {
        wxA[i] = W_ih[j0 * II + i];
        wxB[i] = W_ih[(j0 + 1) * II + i];
    }
    const float biasA = b_ih[j0] + b_hh[j0];
    const float biasB = b_ih[j0 + 1] + b_hh[j0 + 1];

    // ---- init h (f16) ----
    {
        f16x2 hi;
        hi.x = (_Float16)h0[b * HH + j0];
        hi.y = (_Float16)h0[b * HH + j0 + 1];
        ((unsigned int*)hl)[l] = __builtin_bit_cast(unsigned int, hi);
    }
    // single wave: DS in-order per wave; no barrier needed anywhere.

    const float* xg = x + (size_t)b * TT * II;
    f32x4 xa0 = *(const f32x4*)(xg + 0 * II), xb0 = *(const f32x4*)(xg + 0 * II + 4);
    f32x4 xa1 = *(const f32x4*)(xg + 1 * II), xb1 = *(const f32x4*)(xg + 1 * II + 4);

    float hA = 0.0f, hB = 0.0f;     // final f32 h values (epilogue)

    #define STEP(XA, XB, TN)                                                  \
    {                                                                         \
        float aA0 = biasA, aA1 = 0.0f, aB0 = biasB, aB1 = 0.0f;               \
        /* x-projection, f32 */                                               \
        aA0 = fmaf(XA.x, wxA[0], aA0); aB0 = fmaf(XA.x, wxB[0], aB0);         \
        aA1 = fmaf(XA.y, wxA[1], aA1); aB1 = fmaf(XA.y, wxB[1], aB1);         \
        aA0 = fmaf(XA.z, wxA[2], aA0); aB0 = fmaf(XA.z, wxB[2], aB0);         \
        aA1 = fmaf(XA.w, wxA[3], aA1); aB1 = fmaf(XA.w, wxB[3], aB1);         \
        aA0 = fmaf(XB.x, wxA[4], aA0); aB0 = fmaf(XB.x, wxB[4], aB0);         \
        aA1 = fmaf(XB.y, wxA[5], aA1); aB1 = fmaf(XB.y, wxB[5], aB1);         \
        aA0 = fmaf(XB.z, wxA[6], aA0); aB0 = fmaf(XB.z, wxB[6], aB0);         \
        aA1 = fmaf(XB.w, wxA[7], aA1); aB1 = fmaf(XB.w, wxB[7], aB1);         \
        /* h dot: 16 broadcast b128 reads, 128 fdot2 (f32 accum) */           \
        const uint4* hp = (const uint4*)hl;                                   \
        _Pragma("unroll")                                                     \
        for (int q = 0; q < 16; ++q) {                                        \
            const uint4 u = hp[q];                                            \
            const f16x2 p0 = __builtin_bit_cast(f16x2, u.x);                  \
            const f16x2 p1 = __builtin_bit_cast(f16x2, u.y);                  \
            const f16x2 p2 = __builtin_bit_cast(f16x2, u.z);                  \
            const f16x2 p3 = __builtin_bit_cast(f16x2, u.w);                  \
            FDOT2(p0, wA[4 * q + 0], aA0);                                    \
            FDOT2(p1, wA[4 * q + 1], aA1);                                    \
            FDOT2(p2, wA[4 * q + 2], aA0);                                    \
            FDOT2(p3, wA[4 * q + 3], aA1);                                    \
            FDOT2(p0, wB[4 * q + 0], aB0);                                    \
            FDOT2(p1, wB[4 * q + 1], aB1);                                    \
            FDOT2(p2, wB[4 * q + 2], aB0);                                    \
            FDOT2(p3, wB[4 * q + 3], aB1);                                    \
        }                                                                     \
        const float sA = aA0 + aA1;                                           \
        const float sB = aB0 + aB1;                                           \
        /* tanh(s) = 1 - 2/(2^(2*log2e*s)+1) */                               \
        const float eA = __builtin_amdgcn_exp2f(sA * 2.8853900817779268f);    \
        const float eB = __builtin_amdgcn_exp2f(sB * 2.8853900817779268f);    \
        hA = 1.0f - 2.0f * __builtin_amdgcn_rcpf(eA + 1.0f);                  \
        hB = 1.0f - 2.0f * __builtin_amdgcn_rcpf(eB + 1.0f);                  \
        f16x2 hw; hw.x = (_Float16)hA; hw.y = (_Float16)hB;                   \
        ((unsigned int*)hl)[l] = __builtin_bit_cast(unsigned int, hw);        \
        /* refill x slot (TN steps ahead; floats across steps, no vmcnt) */   \
        { const int tn_ = (TN) < TT ? (TN) : (TT - 1);                        \
          XA = *(const f32x4*)(xg + (size_t)tn_ * II);                        \
          XB = *(const f32x4*)(xg + (size_t)tn_ * II + 4); }                  \
    }

    for (int t = 0; t < TT; t += 2) {
        STEP(xa0, xb0, t + 2)
        STEP(xa1, xb1, t + 3)
    }
    #undef STEP

    // ---- epilogue ----
    *(f32x2*)&out[BB + (size_t)b * HH + j0]           = (f32x2){hA, hB}; // feats
    *(f32x2*)&out[BB + BB * HH + (size_t)b * HH + j0] = (f32x2){hA, hB}; // h_n
    float p = hA * W_head[j0] + hB * W_head[j0 + 1];
    #pragma unroll
    for (int off = 32; off > 0; off >>= 1) p += __shfl_down(p, off);
    if (l == 0) out[b] = p + b_head[0];
}

extern "C" void kernel_launch(void* const* d_in, const int* in_sizes, int n_in,
                              void* d_out, int out_size, void* d_ws, size_t ws_size,
                              hipStream_t stream) {
    const float* x      = (const float*)d_in[0];
    const float* h0     = (const float*)d_in[1];
    const float* W_ih   = (const float*)d_in[2];
    const float* W_hh   = (const float*)d_in[3];
    const float* b_ih   = (const float*)d_in[4];
    const float* b_hh   = (const float*)d_in[5];
    const float* W_head = (const float*)d_in[6];
    const float* b_head = (const float*)d_in[7];
    float* out = (float*)d_out;

    hipLaunchKernelGGL(rnn_v16_kernel, dim3(BB), dim3(64), 0, stream,
                       x, h0, W_ih, W_hh, b_ih, b_hh, W_head, b_head, out);
}

// Round 19
// 607.193 us; speedup vs baseline: 1.7248x; 1.7248x over previous
//
#include <hip/hip_runtime.h>

// SimpleRNN: x(256,2048,8) f32, h(1,256,128), W_ih(128,8), W_hh(128,128),
// b_ih(128), b_hh(128), W_head(1,128), b_head(1)
// out = [pred(256) | last_step_features(256,128) | h_n(256,128)]  (f32)
//
// R17 = R10 (576us, best, verified) with ONE delta: h read as ds_read_b64
// pairs instead of b128+shufflevector. Each f32x2 lands in an even-aligned
// VGPR pair consumed DIRECTLY by the v_pk_fma_f32 asm => the ~32 operand-
// marshalling v_movs per step (R16 post-mortem: VALUBusy says 115 insts/
// lane/step vs ~50 in source) disappear. DS cycles unchanged (16 x ~6cy
// b64 == 8 x 12cy b128, m134); bank pattern unchanged (rotation keeps the
// 4 kc groups on disjoint banks; 16-lane broadcast per address).
// Arithmetic order bit-identical to R10.

typedef float f32x2 __attribute__((ext_vector_type(2)));

#define BB 256
#define TT 2048
#define II 8
#define HH 128
#define THREADS 256

// v_pk_fma_f32, src0 LO/HI half broadcast to both halves (R4/R10-verified)
#define PK_FMA_LO(acc, hp, wp) \
    asm("v_pk_fma_f32 %0, %1, %2, %0 op_sel:[0,0,0] op_sel_hi:[0,1,1]" \
        : "+v"(acc) : "v"(hp), "v"(wp))
#define PK_FMA_HI(acc, hp, wp) \
    asm("v_pk_fma_f32 %0, %1, %2, %0 op_sel:[1,0,0] op_sel_hi:[1,1,1]" \
        : "+v"(acc) : "v"(hp), "v"(wp))

__device__ __forceinline__ float quad_sum(float x) {
    // xor1 + xor2 butterfly within each aligned 4-lane quad (verified)
    int xi = __builtin_bit_cast(int, x);
    int y1 = __builtin_amdgcn_update_dpp(0, xi, 0xB1, 0xF, 0xF, true); // [1,0,3,2]
    float s1 = x + __builtin_bit_cast(float, y1);
    int s1i = __builtin_bit_cast(int, s1);
    int y2 = __builtin_amdgcn_update_dpp(0, s1i, 0x4E, 0xF, 0xF, true); // [2,3,0,1]
    return s1 + __builtin_bit_cast(float, y2);
}

__launch_bounds__(THREADS, 1)
__global__ void rnn_v17_kernel(const float* __restrict__ x,
                               const float* __restrict__ h0,
                               const float* __restrict__ W_ih,
                               const float* __restrict__ W_hh,
                               const float* __restrict__ b_ih,
                               const float* __restrict__ b_hh,
                               const float* __restrict__ W_head,
                               const float* __restrict__ b_head,
                               float* __restrict__ out)
{
    __shared__ __align__(16) float h_lds[2][HH];   // ping-pong hidden state
    __shared__ float part[HH];

    const int b    = blockIdx.x;
    const int tid  = threadIdx.x;
    const int w    = tid >> 6;        // wave 0..3
    const int lane = tid & 63;
    const int jg   = lane >> 2;       // 0..15
    const int kc   = lane & 3;        // 0..3 (32-float k-chunk)
    const int j0   = w * 32 + jg * 2; // this lane's 2 outputs: j0, j0+1

    // weights in READ order (rotation (i+2kc)&7 baked into slot index):
    // wj[4i+c] = (W_hh[j0][kc*32+4m+c], W_hh[j0+1][kc*32+4m+c]), m=(i+2kc)&7
    f32x2 wj[32];
    {
        const float* r0 = W_hh + (size_t)j0 * HH + kc * 32;
        const float* r1 = r0 + HH;
        #pragma unroll
        for (int i = 0; i < 8; ++i) {
            const int m = (i + 2 * kc) & 7;
            #pragma unroll
            for (int c = 0; c < 4; ++c)
                wj[4 * i + c] = (f32x2){r0[4 * m + c], r1[4 * m + c]};
        }
    }
    f32x2 wx0 = (f32x2){W_ih[j0 * II + 2 * kc],     W_ih[(j0 + 1) * II + 2 * kc]};
    f32x2 wx1 = (f32x2){W_ih[j0 * II + 2 * kc + 1], W_ih[(j0 + 1) * II + 2 * kc + 1]};
    f32x2 bias2 = (f32x2){0.25f * (b_ih[j0] + b_hh[j0]),
                          0.25f * (b_ih[j0 + 1] + b_hh[j0 + 1])};

    if (tid < HH) h_lds[0][tid] = h0[b * HH + tid];
    __syncthreads();

    // x: direct global f32x2 loads, 2-step register pipeline (R10-verified)
    const float* xk = x + (size_t)b * TT * II + 2 * kc;
    f32x2 xe = *(const f32x2*)(xk + 0 * II);
    f32x2 xo = *(const f32x2*)(xk + 1 * II);

    #define STEP(XV, RBUF, TN)                                                   \
    {                                                                            \
        f32x2 a0 = bias2;                                                        \
        f32x2 a1 = (f32x2){0.f, 0.f};                                            \
        f32x2 a2 = (f32x2){0.f, 0.f};                                            \
        f32x2 a3 = (f32x2){0.f, 0.f};                                            \
        PK_FMA_LO(a0, XV, wx0);          /* x[2kc]   * W_ih col for j0,j1 */     \
        PK_FMA_HI(a1, XV, wx1);          /* x[2kc+1] * W_ih col for j0,j1 */     \
        _Pragma("unroll")                                                        \
        for (int i = 0; i < 8; ++i) {                                            \
            const int m = (i + 2 * kc) & 7;                                      \
            const f32x2 h01 = *(const f32x2*)&h_lds[RBUF][kc * 32 + 4 * m];      \
            const f32x2 h23 = *(const f32x2*)&h_lds[RBUF][kc * 32 + 4 * m + 2];  \
            PK_FMA_LO(a0, h01, wj[4 * i + 0]);                                   \
            PK_FMA_HI(a1, h01, wj[4 * i + 1]);                                   \
            PK_FMA_LO(a2, h23, wj[4 * i + 2]);                                   \
            PK_FMA_HI(a3, h23, wj[4 * i + 3]);                                   \
        }                                                                        \
        const f32x2 s2 = (a0 + a1) + (a2 + a3);   /* v_pk_add_f32 x3 */          \
        const float s0 = quad_sum(s2.x);                                         \
        const float s1 = quad_sum(s2.y);                                         \
        const float e0 = __builtin_amdgcn_exp2f(s0 * 2.8853900817779268f);       \
        const float e1 = __builtin_amdgcn_exp2f(s1 * 2.8853900817779268f);       \
        f32x2 hn;                                                                \
        hn.x = 1.0f - 2.0f * __builtin_amdgcn_rcpf(e0 + 1.0f);                   \
        hn.y = 1.0f - 2.0f * __builtin_amdgcn_rcpf(e1 + 1.0f);                   \
        if (kc == 0) *(f32x2*)&h_lds[(RBUF) ^ 1][j0] = hn;                       \
        { const int tn_ = (TN) < TT ? (TN) : (TT - 1);                           \
          XV = *(const f32x2*)(xk + (size_t)tn_ * II); }                         \
        asm volatile("s_waitcnt lgkmcnt(0)\n\ts_barrier" ::: "memory");          \
    }

    for (int t = 0; t < TT; t += 2) {
        STEP(xe, 0, t + 2)   // even step: reads buf0, writes buf1
        STEP(xo, 1, t + 3)   // odd  step: reads buf1, writes buf0
    }
    #undef STEP

    // ---- epilogue: final h in h_lds[0] (t=2047 odd wrote buf 0) ----
    if (tid < HH) {
        const float hl = h_lds[0][tid];
        out[BB + b * HH + tid]           = hl;   // last_step_features
        out[BB + BB * HH + b * HH + tid] = hl;   // h_n
        part[tid] = hl * W_head[tid];
    }
    __syncthreads();
    if (w == 0) {
        float s = part[lane] + part[lane + 64];
        #pragma unroll
        for (int off = 32; off > 0; off >>= 1) s += __shfl_down(s, off);
        if (lane == 0) out[b] = s + b_head[0];
    }
}

extern "C" void kernel_launch(void* const* d_in, const int* in_sizes, int n_in,
                              void* d_out, int out_size, void* d_ws, size_t ws_size,
                              hipStream_t stream) {
    const float* x      = (const float*)d_in[0];
    const float* h0     = (const float*)d_in[1];
    const float* W_ih   = (const float*)d_in[2];
    const float* W_hh   = (const float*)d_in[3];
    const float* b_ih   = (const float*)d_in[4];
    const float* b_hh   = (const float*)d_in[5];
    const float* W_head = (const float*)d_in[6];
    const float* b_head = (const float*)d_in[7];
    float* out = (float*)d_out;

    hipLaunchKernelGGL(rnn_v17_kernel, dim3(BB), dim3(THREADS), 0, stream,
                       x, h0, W_ih, W_hh, b_ih, b_hh, W_head, b_head, out);
}

// Round 20
// 576.272 us; speedup vs baseline: 1.8173x; 1.0537x over previous
//
#include <hip/hip_runtime.h>

// SimpleRNN: x(256,2048,8) f32, h(1,256,128), W_ih(128,8), W_hh(128,128),
// b_ih(128), b_hh(128), W_head(1,128), b_head(1)
// out = [pred(256) | last_step_features(256,128) | h_n(256,128)]  (f32)
//
// R18 = R10 verbatim (verified best: 576us). Restores the record after
// R17's b64 experiment regressed (+5%). Design (all components verified):
//  - 4 waves (1/SIMD), 256 thr: lane=(jg 0..15, kc 0..3), 2 outputs/lane
//    via v_pk_fma_f32 op_sel broadcast.
//  - 8 rotated conflict-free broadcast ds_read_b128 of h per lane-step.
//  - reduce: pure quad-DPP (xor1+xor2), no DS ops on the serial path.
//  - raw s_barrier + lgkmcnt(0) only (no vmcnt drain; x loads float).
//  - x read direct from global (L2-resident), 2-step register pipeline.
//  - ping-pong h in LDS; weights remat-streamed (falsified as bottleneck).
// Structural floor of the family: ~675 cy/step serial handoff
// (write+drain+barrier+read-latency+FMA-chain+reduce+tanh); wave-count
// scan {1,2,4,8} -> 4 optimal; all alternative structures measured worse.

typedef float f32x2 __attribute__((ext_vector_type(2)));
typedef float f32x4 __attribute__((ext_vector_type(4)));

#define BB 256
#define TT 2048
#define II 8
#define HH 128
#define THREADS 256

// v_pk_fma_f32, src0 LO/HI broadcast to both halves (R4-verified encodings)
#define PK_FMA_LO(acc, hp, wp) \
    asm("v_pk_fma_f32 %0, %1, %2, %0 op_sel:[0,0,0] op_sel_hi:[0,1,1]" \
        : "+v"(acc) : "v"(hp), "v"(wp))
#define PK_FMA_HI(acc, hp, wp) \
    asm("v_pk_fma_f32 %0, %1, %2, %0 op_sel:[1,0,0] op_sel_hi:[1,1,1]" \
        : "+v"(acc) : "v"(hp), "v"(wp))

__device__ __forceinline__ float quad_sum(float x) {
    // xor1 + xor2 butterfly within each aligned 4-lane quad (DPP only)
    int xi = __builtin_bit_cast(int, x);
    int y1 = __builtin_amdgcn_update_dpp(0, xi, 0xB1, 0xF, 0xF, true); // [1,0,3,2]
    float s1 = x + __builtin_bit_cast(float, y1);
    int s1i = __builtin_bit_cast(int, s1);
    int y2 = __builtin_amdgcn_update_dpp(0, s1i, 0x4E, 0xF, 0xF, true); // [2,3,0,1]
    return s1 + __builtin_bit_cast(float, y2);
}

__launch_bounds__(THREADS, 1)
__global__ void rnn_v18_kernel(const float* __restrict__ x,
                               const float* __restrict__ h0,
                               const float* __restrict__ W_ih,
                               const float* __restrict__ W_hh,
                               const float* __restrict__ b_ih,
                               const float* __restrict__ b_hh,
                               const float* __restrict__ W_head,
                               const float* __restrict__ b_head,
                               float* __restrict__ out)
{
    __shared__ __align__(16) float h_lds[2][HH];   // ping-pong hidden state
    __shared__ float part[HH];

    const int b    = blockIdx.x;
    const int tid  = threadIdx.x;
    const int w    = tid >> 6;        // wave 0..3
    const int lane = tid & 63;
    const int jg   = lane >> 2;       // 0..15
    const int kc   = lane & 3;        // 0..3 (32-k chunk)
    const int j0   = w * 32 + jg * 2; // this lane's 2 outputs: j0, j0+1

    // ---- weights in READ order (rotation (i+2kc)&7 baked into slot index):
    // wj[4i+c] = (W_hh[j0][kc*32+4m+c], W_hh[j0+1][kc*32+4m+c]), m=(i+2kc)&7
    f32x2 wj[32];
    {
        const float* r0 = W_hh + (size_t)j0 * HH + kc * 32;
        const float* r1 = r0 + HH;
        #pragma unroll
        for (int i = 0; i < 8; ++i) {
            const int m = (i + 2 * kc) & 7;
            #pragma unroll
            for (int c = 0; c < 4; ++c)
                wj[4 * i + c] = (f32x2){r0[4 * m + c], r1[4 * m + c]};
        }
    }
    f32x2 wx0 = (f32x2){W_ih[j0 * II + 2 * kc],     W_ih[(j0 + 1) * II + 2 * kc]};
    f32x2 wx1 = (f32x2){W_ih[j0 * II + 2 * kc + 1], W_ih[(j0 + 1) * II + 2 * kc + 1]};
    f32x2 bias2 = (f32x2){0.25f * (b_ih[j0] + b_hh[j0]),
                          0.25f * (b_ih[j0 + 1] + b_hh[j0 + 1])};

    if (tid < HH) h_lds[0][tid] = h0[b * HH + tid];
    __syncthreads();

    // x: direct global reads, 2-step register pipeline (L2-resident, vmcnt
    // never drained in-loop so these float across barriers)
    const float* xk = x + (size_t)b * TT * II + 2 * kc;
    f32x2 xe = *(const f32x2*)(xk + 0 * II);
    f32x2 xo = *(const f32x2*)(xk + 1 * II);

    #define STEP(XV, RBUF, TN)                                                   \
    {                                                                            \
        f32x2 a0 = bias2;                                                        \
        f32x2 a1 = (f32x2){0.f, 0.f};                                            \
        f32x2 a2 = (f32x2){0.f, 0.f};                                            \
        f32x2 a3 = (f32x2){0.f, 0.f};                                            \
        PK_FMA_LO(a0, XV, wx0);          /* x[2kc]   * W_ih col for j0,j1 */     \
        PK_FMA_HI(a1, XV, wx1);          /* x[2kc+1] * W_ih col for j0,j1 */     \
        _Pragma("unroll")                                                        \
        for (int i = 0; i < 8; i += 2) {                                         \
            const f32x4 hva = *(const f32x4*)                                    \
                &h_lds[RBUF][kc * 32 + (((i + 0) + 2 * kc) & 7) * 4];            \
            const f32x4 hvb = *(const f32x4*)                                    \
                &h_lds[RBUF][kc * 32 + (((i + 1) + 2 * kc) & 7) * 4];            \
            const f32x2 ha01 = __builtin_shufflevector(hva, hva, 0, 1);          \
            const f32x2 ha23 = __builtin_shufflevector(hva, hva, 2, 3);          \
            const f32x2 hb01 = __builtin_shufflevector(hvb, hvb, 0, 1);          \
            const f32x2 hb23 = __builtin_shufflevector(hvb, hvb, 2, 3);          \
            PK_FMA_LO(a0, ha01, wj[4 * i + 0]);                                  \
            PK_FMA_HI(a1, ha01, wj[4 * i + 1]);                                  \
            PK_FMA_LO(a2, ha23, wj[4 * i + 2]);                                  \
            PK_FMA_HI(a3, ha23, wj[4 * i + 3]);                                  \
            PK_FMA_LO(a0, hb01, wj[4 * i + 4]);                                  \
            PK_FMA_HI(a1, hb01, wj[4 * i + 5]);                                  \
            PK_FMA_LO(a2, hb23, wj[4 * i + 6]);                                  \
            PK_FMA_HI(a3, hb23, wj[4 * i + 7]);                                  \
        }                                                                        \
        const f32x2 s2 = (a0 + a1) + (a2 + a3);   /* v_pk_add_f32 x3 */          \
        const float s0 = quad_sum(s2.x);                                         \
        const float s1 = quad_sum(s2.y);                                         \
        const float e0 = __builtin_amdgcn_exp2f(s0 * 2.8853900817779268f);       \
        const float e1 = __builtin_amdgcn_exp2f(s1 * 2.8853900817779268f);       \
        f32x2 hn;                                                                \
        hn.x = 1.0f - 2.0f * __builtin_amdgcn_rcpf(e0 + 1.0f);                   \
        hn.y = 1.0f - 2.0f * __builtin_amdgcn_rcpf(e1 + 1.0f);                   \
        if (kc == 0) *(f32x2*)&h_lds[(RBUF) ^ 1][j0] = hn;                       \
        { const int tn_ = (TN) < TT ? (TN) : (TT - 1);                           \
          XV = *(const f32x2*)(xk + (size_t)tn_ * II); }                         \
        asm volatile("s_waitcnt lgkmcnt(0)\n\ts_barrier" ::: "memory");          \
    }

    for (int t = 0; t < TT; t += 2) {
        STEP(xe, 0, t + 2)   // even step: reads buf0, writes buf1
        STEP(xo, 1, t + 3)   // odd  step: reads buf1, writes buf0
    }
    #undef STEP

    // ---- epilogue: final h in h_lds[0] (t=2047 odd wrote buf 0) ----
    if (tid < HH) {
        const float hl = h_lds[0][tid];
        out[BB + b * HH + tid]           = hl;   // last_step_features
        out[BB + BB * HH + b * HH + tid] = hl;   // h_n
        part[tid] = hl * W_head[tid];
    }
    __syncthreads();
    if (w == 0) {
        float s = part[lane] + part[lane + 64];
        #pragma unroll
        for (int off = 32; off > 0; off >>= 1) s += __shfl_down(s, off);
        if (lane == 0) out[b] = s + b_head[0];
    }
}

extern "C" void kernel_launch(void* const* d_in, const int* in_sizes, int n_in,
                              void* d_out, int out_size, void* d_ws, size_t ws_size,
                              hipStream_t stream) {
    const float* x      = (const float*)d_in[0];
    const float* h0     = (const float*)d_in[1];
    const float* W_ih   = (const float*)d_in[2];
    const float* W_hh   = (const float*)d_in[3];
    const float* b_ih   = (const float*)d_in[4];
    const float* b_hh   = (const float*)d_in[5];
    const float* W_head = (const float*)d_in[6];
    const float* b_head = (const float*)d_in[7];
    float* out = (float*)d_out;

    hipLaunchKernelGGL(rnn_v18_kernel, dim3(BB), dim3(THREADS), 0, stream,
                       x, h0, W_ih, W_hh, b_ih, b_hh, W_head, b_head, out);
}